// Round 2
// baseline (1020.087 us; speedup 1.0000x reference)
//
#include <hip/hip_runtime.h>
#include <math.h>

// ---------------- problem constants ----------------
#define B_    4
#define S_    896
#define D_    1024
#define H_    16
#define I_    4096
#define OUT_  4096
#define L_    2
#define M_    128
#define T_    1024           // M_ + S_
#define NROW  4096           // B_ * T_
#define DH    64             // D_/H_

typedef unsigned short u16;
typedef unsigned int   u32;
typedef float  f32x4  __attribute__((ext_vector_type(4)));
typedef __bf16 bf16x8 __attribute__((ext_vector_type(8)));
typedef u16    u16x2  __attribute__((ext_vector_type(2)));
typedef u16    u16x4  __attribute__((ext_vector_type(4)));

typedef __attribute__((address_space(1))) const void gvoid;
typedef __attribute__((address_space(3))) void       lvoid;

__device__ __forceinline__ u16 f2bf(float f) {
  u32 u = __builtin_bit_cast(u32, f);
  u = (u + 0x7fffu + ((u >> 16) & 1u)) >> 16;   // RNE; inputs are tame (no inf/nan)
  return (u16)u;
}
__device__ __forceinline__ float geluf(float v) {
  return 0.5f * v * (1.0f + erff(v * 0.70710678118654752f));
}
__device__ __forceinline__ void gld16(const void* g, void* l) {
  // async global->LDS, dest = wave-uniform base + lane*16 (linear, no swizzle)
  __builtin_amdgcn_global_load_lds((gvoid*)g, (lvoid*)l, 16, 0, 0);
}

// ---------------- build x = concat(mem, hidden) ----------------
__global__ __launch_bounds__(256) void build_x(const float* __restrict__ hs,
                                               const float* __restrict__ mem,
                                               float* __restrict__ xf,
                                               u16* __restrict__ xb) {
  const long i  = (long)blockIdx.x * 256 + threadIdx.x;   // float4 index
  const int row = (int)(i >> 8);
  const int c4  = (int)(i & 255);
  const int bb  = row >> 10, t = row & 1023;
  f32x4 v;
  if (t < M_) v = ((const f32x4*)(mem + (long)t * D_))[c4];
  else        v = ((const f32x4*)(hs + (long)(bb * S_ + (t - M_)) * D_))[c4];
  ((f32x4*)xf)[i] = v;
  u16x4 ob;
  #pragma unroll
  for (int c = 0; c < 4; c++) ob[c] = f2bf(v[c]);
  ((u16x4*)xb)[i] = ob;
}

// ---------------- weight transpose fp32(KxN) -> bf16(NxK) ----------------
__global__ __launch_bounds__(256) void wtrans(const float* __restrict__ W,
                                              u16* __restrict__ WT, int K, int N) {
  __shared__ float t[32][33];
  const int n0 = blockIdx.x * 32, k0 = blockIdx.y * 32;
  const int tx = threadIdx.x, ty = threadIdx.y;
  #pragma unroll
  for (int r = 0; r < 32; r += 8)
    t[ty + r][tx] = W[(long)(k0 + ty + r) * N + n0 + tx];
  __syncthreads();
  #pragma unroll
  for (int r = 0; r < 32; r += 8)
    WT[(long)(n0 + ty + r) * K + k0 + tx] = f2bf(t[tx][ty + r]);
}

// ---------------- LayerNorm: y -> xf (fp32) + xb (bf16) ----------------
__global__ __launch_bounds__(256) void ln_k(const float* __restrict__ y,
                                            const float* __restrict__ ga,
                                            const float* __restrict__ be,
                                            float* __restrict__ xf,
                                            u16* __restrict__ xb) {
  const int row = blockIdx.x, tid = threadIdx.x;
  const f32x4 v = ((const f32x4*)(y + (long)row * D_))[tid];
  float s  = v[0] + v[1] + v[2] + v[3];
  float ss = v[0]*v[0] + v[1]*v[1] + v[2]*v[2] + v[3]*v[3];
  #pragma unroll
  for (int m = 1; m < 64; m <<= 1) { s += __shfl_xor(s, m); ss += __shfl_xor(ss, m); }
  __shared__ float sm[8];
  if ((tid & 63) == 0) { sm[tid >> 6] = s; sm[4 + (tid >> 6)] = ss; }
  __syncthreads();
  s  = sm[0] + sm[1] + sm[2] + sm[3];
  ss = sm[4] + sm[5] + sm[6] + sm[7];
  const float mu  = s * (1.0f / D_);
  const float var = ss * (1.0f / D_) - mu * mu;
  const float rs  = rsqrtf(var + 1e-12f);
  const f32x4 gg = ((const f32x4*)ga)[tid];
  const f32x4 bb = ((const f32x4*)be)[tid];
  f32x4 o; u16x4 ob;
  #pragma unroll
  for (int c = 0; c < 4; c++) { o[c] = (v[c] - mu) * rs * gg[c] + bb[c]; ob[c] = f2bf(o[c]); }
  ((f32x4*)(xf + (long)row * D_))[tid] = o;
  ((u16x4*)(xb + (long)row * D_))[tid] = ob;
}

// ---------------- copy read_out ----------------
__global__ __launch_bounds__(256) void copy_ro(const float* __restrict__ xf,
                                               float* __restrict__ dst) {
  const long i  = (long)blockIdx.x * 256 + threadIdx.x;   // float4 idx
  const int row = (int)(i >> 8);
  const int c4  = (int)(i & 255);
  const int bb  = row >> 7, t = row & 127;
  f32x4 v = ((const f32x4*)(xf + (long)(bb * T_ + t) * D_))[c4];
  ((f32x4*)dst)[i] = v;
}

// ---------------- GEMM: C = A(bf16 MxK) @ BT(bf16 NxK)^T, m97 structure ----------------
// EPI: 0=QKV scatter  1=bias+residual->f32  2=bias+gelu->bf16  3=bias+gelu->f32
// RMAP: 1 = final projector A-row remap (skip mem rows)
template <int EPI, int RMAP>
__global__ __launch_bounds__(256) void gemm_bt(const u16* __restrict__ A,
                                               const u16* __restrict__ BT,
                                               const float* __restrict__ bias0,
                                               const float* __restrict__ bias1,
                                               const float* __restrict__ bias2,
                                               const float* __restrict__ resid,
                                               float* __restrict__ of,
                                               u16* __restrict__ ob0,
                                               u16* __restrict__ ob1,
                                               u16* __restrict__ ob2,
                                               int M, int N, int K) {
  __shared__ u16 As[128 * 32];
  __shared__ u16 Bs[128 * 32];
  const int tid = threadIdx.x;
  const int l   = tid & 63;
  const int w   = tid >> 6;
  const int r16 = l & 15;
  const int g   = l >> 4;
  const int bm = blockIdx.x, bn = blockIdx.y;

  // staging coords: chunk(w)/(w+4), each lane 16B
  const int srow0 = w * 16 + (l >> 2);
  const int srow1 = srow0 + 64;
  const int scol  = (l & 3) * 8;
  long ar0 = (long)bm * 128 + srow0;
  long ar1 = (long)bm * 128 + srow1;
  if (RMAP == 1) {                       // R -> b*1024 + 128 + R%896
    int R0 = (int)ar0, R1 = (int)ar1;
    ar0 = (long)(R0 / 896) * 1024 + 128 + (R0 % 896);
    ar1 = (long)(R1 / 896) * 1024 + 128 + (R1 % 896);
  }
  const u16* Ag0 = A + ar0 * K + scol;
  const u16* Ag1 = A + ar1 * K + scol;
  const u16* Bg0 = BT + ((long)bn * 128 + srow0) * K + scol;
  const u16* Bg1 = BT + ((long)bn * 128 + srow1) * K + scol;
  u16* AsD0 = As + w * 512; u16* AsD1 = As + (w + 4) * 512;
  u16* BsD0 = Bs + w * 512; u16* BsD1 = Bs + (w + 4) * 512;

  const int wm = w >> 1, wn = w & 1;
  const int aro = (wm * 64 + r16) * 32 + g * 8;
  const int bro = (wn * 64 + r16) * 32 + g * 8;

  f32x4 acc[4][4];
  #pragma unroll
  for (int i = 0; i < 4; i++)
    #pragma unroll
    for (int j = 0; j < 4; j++) acc[i][j] = (f32x4){0.f, 0.f, 0.f, 0.f};

  for (int k0 = 0; k0 < K; k0 += 32) {
    gld16(Ag0 + k0, AsD0);
    gld16(Ag1 + k0, AsD1);
    gld16(Bg0 + k0, BsD0);
    gld16(Bg1 + k0, BsD1);
    __syncthreads();                      // vmcnt drained by compiler before barrier
    bf16x8 af[4], bfr[4];
    #pragma unroll
    for (int i = 0; i < 4; i++) af[i]  = *(const bf16x8*)&As[aro + i * 512];
    #pragma unroll
    for (int j = 0; j < 4; j++) bfr[j] = *(const bf16x8*)&Bs[bro + j * 512];
    #pragma unroll
    for (int i = 0; i < 4; i++)
      #pragma unroll
      for (int j = 0; j < 4; j++)
        acc[i][j] = __builtin_amdgcn_mfma_f32_16x16x32_bf16(af[i], bfr[j], acc[i][j], 0, 0, 0);
    __syncthreads();
  }

  // epilogue: C[row=(l>>4)*4+rr][col=l&15] per 16x16 tile (m89/m91 layout)
  #pragma unroll
  for (int i = 0; i < 4; i++) {
    const int grow0 = bm * 128 + wm * 64 + i * 16 + g * 4;
    #pragma unroll
    for (int j = 0; j < 4; j++) {
      const int gcol = bn * 128 + wn * 64 + j * 16 + r16;
      f32x4 v = acc[i][j];
      if (EPI == 0) {
        const int bb = grow0 >> 10, t0 = grow0 & 1023;
        if (gcol < 1024) {                       // Q (pre-scaled by 1/8)
          const float bi = bias0[gcol];
          const int h = gcol >> 6, d = gcol & 63;
          u16* dst = ob0 + ((long)(bb * H_ + h) * T_) * DH + d;
          #pragma unroll
          for (int rr = 0; rr < 4; rr++) dst[(long)(t0 + rr) * DH] = f2bf((v[rr] + bi) * 0.125f);
        } else if (gcol < 2048) {                // K
          const int c = gcol - 1024;
          const float bi = bias1[c];
          const int h = c >> 6, d = c & 63;
          u16* dst = ob1 + ((long)(bb * H_ + h) * T_) * DH + d;
          #pragma unroll
          for (int rr = 0; rr < 4; rr++) dst[(long)(t0 + rr) * DH] = f2bf(v[rr] + bi);
        } else {                                 // V -> transposed (bh, d, t)
          const int c = gcol - 2048;
          const float bi = bias2[c];
          const int h = c >> 6, d = c & 63;
          u16x4 pk;
          #pragma unroll
          for (int rr = 0; rr < 4; rr++) pk[rr] = f2bf(v[rr] + bi);
          *(u16x4*)(ob2 + ((long)(bb * H_ + h) * DH + d) * T_ + t0) = pk;
        }
      } else if (EPI == 1) {
        const float bi = bias0[gcol];
        #pragma unroll
        for (int rr = 0; rr < 4; rr++) {
          const long idx = (long)(grow0 + rr) * N + gcol;
          of[idx] = v[rr] + bi + resid[idx];
        }
      } else if (EPI == 2) {
        const float bi = bias0[gcol];
        #pragma unroll
        for (int rr = 0; rr < 4; rr++)
          ob0[(long)(grow0 + rr) * N + gcol] = f2bf(geluf(v[rr] + bi));
      } else {
        const float bi = bias0[gcol];
        #pragma unroll
        for (int rr = 0; rr < 4; rr++)
          of[(long)(grow0 + rr) * N + gcol] = geluf(v[rr] + bi);
      }
    }
  }
}

// ---------------- fused flash attention ----------------
// One wave = 16 q-rows of one (b,h). Swapped S^T = mfma(K,Q) so each lane's
// softmax row (q = l&15) reduces with 2 shuffles; PV computed as V^T @ P^T.
__global__ __launch_bounds__(256) void attn_k(const u16* __restrict__ qB,
                                              const u16* __restrict__ kB,
                                              const u16* __restrict__ vT,
                                              u16* __restrict__ ctx) {
  const int l = threadIdx.x & 63, w = threadIdx.x >> 6;
  const int r16 = l & 15, g = l >> 4;
  const int bh = blockIdx.y;
  const int bb = bh >> 4, h = bh & 15;
  const int qbase = blockIdx.x * 64 + w * 16;
  const u16* qh = qB + (long)bh * T_ * DH;
  const u16* kh = kB + (long)bh * T_ * DH;
  const u16* vh = vT + (long)bh * DH * T_;

  const bf16x8 qf0 = *(const bf16x8*)&qh[(qbase + r16) * DH + g * 8];
  const bf16x8 qf1 = *(const bf16x8*)&qh[(qbase + r16) * DH + 32 + g * 8];

  f32x4 ot[4];
  #pragma unroll
  for (int i = 0; i < 4; i++) ot[i] = (f32x4){0.f, 0.f, 0.f, 0.f};
  float mrow = -1e30f, lrow = 0.f;

  for (int kb0 = 0; kb0 < T_; kb0 += 32) {
    f32x4 s0 = {0.f, 0.f, 0.f, 0.f}, s1 = {0.f, 0.f, 0.f, 0.f};
    {
      bf16x8 a0 = *(const bf16x8*)&kh[(kb0 + r16) * DH + g * 8];
      bf16x8 a1 = *(const bf16x8*)&kh[(kb0 + r16) * DH + 32 + g * 8];
      s0 = __builtin_amdgcn_mfma_f32_16x16x32_bf16(a0, qf0, s0, 0, 0, 0);
      s0 = __builtin_amdgcn_mfma_f32_16x16x32_bf16(a1, qf1, s0, 0, 0, 0);
    }
    {
      bf16x8 a0 = *(const bf16x8*)&kh[(kb0 + 16 + r16) * DH + g * 8];
      bf16x8 a1 = *(const bf16x8*)&kh[(kb0 + 16 + r16) * DH + 32 + g * 8];
      s1 = __builtin_amdgcn_mfma_f32_16x16x32_bf16(a0, qf0, s1, 0, 0, 0);
      s1 = __builtin_amdgcn_mfma_f32_16x16x32_bf16(a1, qf1, s1, 0, 0, 0);
    }
    // online softmax: lane holds 8 scores (keys g*4+r, 16+g*4+r) for q = l&15
    float smax = fmaxf(fmaxf(fmaxf(s0[0], s0[1]), fmaxf(s0[2], s0[3])),
                       fmaxf(fmaxf(s1[0], s1[1]), fmaxf(s1[2], s1[3])));
    smax = fmaxf(smax, __shfl_xor(smax, 16));
    smax = fmaxf(smax, __shfl_xor(smax, 32));
    const float newm = fmaxf(mrow, smax);
    float p0[4], p1[4], ssum = 0.f;
    #pragma unroll
    for (int r = 0; r < 4; r++) {
      p0[r] = __expf(s0[r] - newm);
      p1[r] = __expf(s1[r] - newm);
      ssum += p0[r] + p1[r];
    }
    ssum += __shfl_xor(ssum, 16);
    ssum += __shfl_xor(ssum, 32);
    const float sc = __expf(mrow - newm);
    lrow = lrow * sc + ssum;
    mrow = newm;
    #pragma unroll
    for (int i = 0; i < 4; i++) { ot[i][0] *= sc; ot[i][1] *= sc; ot[i][2] *= sc; ot[i][3] *= sc; }

    // rebuild P^T B-frag (32 keys): dest lane group g needs keys 8g..8g+7
    const u32 w01_0 = (u32)f2bf(p0[0]) | ((u32)f2bf(p0[1]) << 16);
    const u32 w23_0 = (u32)f2bf(p0[2]) | ((u32)f2bf(p0[3]) << 16);
    const u32 w01_1 = (u32)f2bf(p1[0]) | ((u32)f2bf(p1[1]) << 16);
    const u32 w23_1 = (u32)f2bf(p1[2]) | ((u32)f2bf(p1[3]) << 16);
    union { u32 u[4]; bf16x8 v; } pu;
    #pragma unroll
    for (int c = 0; c < 4; c++) {
      const int srcIdx = (2 * (g & 1) + (c >> 1)) * 16 + r16;
      const u32 vA = (u32)__shfl((int)((c & 1) ? w23_0 : w01_0), srcIdx);
      const u32 vB = (u32)__shfl((int)((c & 1) ? w23_1 : w01_1), srcIdx);
      pu.u[c] = (g >> 1) ? vB : vA;
    }
    #pragma unroll
    for (int dt = 0; dt < 4; dt++) {
      bf16x8 vf = *(const bf16x8*)&vh[(dt * 16 + r16) * T_ + kb0 + g * 8];
      ot[dt] = __builtin_amdgcn_mfma_f32_16x16x32_bf16(vf, pu.v, ot[dt], 0, 0, 0);
    }
  }
  const float inv = 1.0f / lrow;
  u16* dst = ctx + ((long)(bb * T_ + qbase + r16)) * D_ + h * DH;
  #pragma unroll
  for (int dt = 0; dt < 4; dt++) {
    const int d = dt * 16 + g * 4;
    u16x2 a; a[0] = f2bf(ot[dt][0] * inv); a[1] = f2bf(ot[dt][1] * inv);
    u16x2 b2; b2[0] = f2bf(ot[dt][2] * inv); b2[1] = f2bf(ot[dt][3] * inv);
    *(u16x2*)(dst + d) = a;
    *(u16x2*)(dst + d + 2) = b2;
  }
}

// ---------------- host ----------------
extern "C" void kernel_launch(void* const* d_in, const int* in_sizes, int n_in,
                              void* d_out, int out_size, void* d_ws, size_t ws_size,
                              hipStream_t stream) {
  const float* hs  = (const float*)d_in[0];
  const float* mem = (const float*)d_in[1];
  const float* Wq  = (const float*)d_in[2];
  const float* bq  = (const float*)d_in[3];
  const float* Wk  = (const float*)d_in[4];
  const float* bk  = (const float*)d_in[5];
  const float* Wv  = (const float*)d_in[6];
  const float* bv  = (const float*)d_in[7];
  const float* Wo  = (const float*)d_in[8];
  const float* bo  = (const float*)d_in[9];
  const float* g1  = (const float*)d_in[10];
  const float* be1 = (const float*)d_in[11];
  const float* Wm  = (const float*)d_in[12];
  const float* bm  = (const float*)d_in[13];
  const float* Wr  = (const float*)d_in[14];
  const float* br  = (const float*)d_in[15];
  const float* g2  = (const float*)d_in[16];
  const float* be2 = (const float*)d_in[17];
  const float* Wp  = (const float*)d_in[18];
  const float* bp  = (const float*)d_in[19];
  float* out = (float*)d_out;

  char* ws = (char*)d_ws;
  float* xf  = (float*)(ws + 0);                 // 16 MB
  u16*   xb  = (u16*)  (ws + 16777216);          //  8 MB
  float* yb  = (float*)(ws + 25165824);          // 16 MB
  u16*   qb  = (u16*)  (ws + 41943040);          //  8 MB
  u16*   kb2 = (u16*)  (ws + 50331648);          //  8 MB
  u16*   vtb = (u16*)  (ws + 58720256);          //  8 MB
  u16*   ctx = (u16*)  (ws + 67108864);          //  8 MB
  u16*   ib  = qb;                               // 32 MB alias (qkv/ctx dead when live)
  u16*   WTqkv = (u16*)(ws + 75497472);          // 12 MB
  u16*   WTo   = (u16*)(ws + 88080384);          //  4 MB
  u16*   WTm   = (u16*)(ws + 92274688);          // 16 MB
  u16*   WTr   = (u16*)(ws + 109051904);         // 16 MB
  u16*   WTp   = (u16*)(ws + 125829120);         //  8 MB  (total 128 MB)

  const dim3 blk(256);
  const dim3 tb(32, 8);

  build_x<<<dim3(4096), blk, 0, stream>>>(hs, mem, xf, xb);

  for (int l = 0; l < L_; l++) {
    wtrans<<<dim3(32, 32), tb, 0, stream>>>(Wq + (long)l * D_ * D_, WTqkv + (long)l * 3072 * 1024, 1024, 1024);
    wtrans<<<dim3(32, 32), tb, 0, stream>>>(Wk + (long)l * D_ * D_, WTqkv + (long)l * 3072 * 1024 + 1024 * 1024, 1024, 1024);
    wtrans<<<dim3(32, 32), tb, 0, stream>>>(Wv + (long)l * D_ * D_, WTqkv + (long)l * 3072 * 1024 + 2048 * 1024, 1024, 1024);
    wtrans<<<dim3(32, 32), tb, 0, stream>>>(Wo + (long)l * D_ * D_, WTo + (long)l * 1024 * 1024, 1024, 1024);
    wtrans<<<dim3(128, 32), tb, 0, stream>>>(Wm + (long)l * D_ * I_, WTm + (long)l * 4096 * 1024, 1024, 4096);
    wtrans<<<dim3(32, 128), tb, 0, stream>>>(Wr + (long)l * I_ * D_, WTr + (long)l * 4096 * 1024, 4096, 1024);
  }
  wtrans<<<dim3(128, 32), tb, 0, stream>>>(Wp, WTp, 1024, 4096);

  for (int l = 0; l < L_; l++) {
    // fused QKV
    gemm_bt<0, 0><<<dim3(32, 24), blk, 0, stream>>>(xb, WTqkv + (long)l * 3072 * 1024,
        bq + l * D_, bk + l * D_, bv + l * D_, nullptr,
        nullptr, qb, kb2, vtb, NROW, 3072, 1024);
    // attention
    attn_k<<<dim3(16, 64), blk, 0, stream>>>(qb, kb2, vtb, ctx);
    // O projection + bias + residual
    gemm_bt<1, 0><<<dim3(32, 8), blk, 0, stream>>>(ctx, WTo + (long)l * 1024 * 1024,
        bo + l * D_, nullptr, nullptr, xf,
        yb, nullptr, nullptr, nullptr, NROW, 1024, 1024);
    ln_k<<<dim3(4096), blk, 0, stream>>>(yb, g1 + l * D_, be1 + l * D_, xf, xb);
    // FFN1 + gelu -> bf16
    gemm_bt<2, 0><<<dim3(32, 32), blk, 0, stream>>>(xb, WTm + (long)l * 4096 * 1024,
        bm + l * I_, nullptr, nullptr, nullptr,
        nullptr, ib, nullptr, nullptr, NROW, 4096, 1024);
    // FFN2 + bias + residual
    gemm_bt<1, 0><<<dim3(32, 8), blk, 0, stream>>>(ib, WTr + (long)l * 4096 * 1024,
        br + l * D_, nullptr, nullptr, xf,
        yb, nullptr, nullptr, nullptr, NROW, 1024, 4096);
    ln_k<<<dim3(4096), blk, 0, stream>>>(yb, g2 + l * D_, be2 + l * D_, xf, xb);
  }

  // final projector on non-mem rows (M=3584=28*128), + gelu -> f32 out
  gemm_bt<3, 1><<<dim3(28, 32), blk, 0, stream>>>(xb, WTp,
      bp, nullptr, nullptr, nullptr,
      out, nullptr, nullptr, nullptr, 3584, 4096, 1024);
  // read_out = x[:, :M]
  copy_ro<<<dim3(512), blk, 0, stream>>>(xf, out + 14680064);
}

// Round 3
// 913.210 us; speedup vs baseline: 1.1170x; 1.1170x over previous
//
#include <hip/hip_runtime.h>
#include <math.h>

// ---------------- problem constants ----------------
#define B_    4
#define S_    896
#define D_    1024
#define H_    16
#define I_    4096
#define OUT_  4096
#define L_    2
#define M_    128
#define T_    1024           // M_ + S_
#define NROW  4096           // B_ * T_
#define DH    64             // D_/H_

typedef unsigned short u16;
typedef unsigned int   u32;
typedef float  f32x4  __attribute__((ext_vector_type(4)));
typedef float  f32x16 __attribute__((ext_vector_type(16)));
typedef __bf16 bf16x8 __attribute__((ext_vector_type(8)));
typedef u16    u16x2  __attribute__((ext_vector_type(2)));
typedef u16    u16x4  __attribute__((ext_vector_type(4)));

typedef __attribute__((address_space(1))) const void gvoid;
typedef __attribute__((address_space(3))) void       lvoid;

__device__ __forceinline__ u16 f2bf(float f) {
  u32 u = __builtin_bit_cast(u32, f);
  u = (u + 0x7fffu + ((u >> 16) & 1u)) >> 16;   // RNE; inputs are tame (no inf/nan)
  return (u16)u;
}
__device__ __forceinline__ float geluf(float v) {
  return 0.5f * v * (1.0f + erff(v * 0.70710678118654752f));
}
__device__ __forceinline__ void gld16(const void* g, void* l) {
  // async global->LDS, dest = wave-uniform base + lane*16 (linear, no swizzle)
  __builtin_amdgcn_global_load_lds((gvoid*)g, (lvoid*)l, 16, 0, 0);
}

// ---------------- build x = concat(mem, hidden) ----------------
__global__ __launch_bounds__(256) void build_x(const float* __restrict__ hs,
                                               const float* __restrict__ mem,
                                               float* __restrict__ xf,
                                               u16* __restrict__ xb) {
  const long i  = (long)blockIdx.x * 256 + threadIdx.x;   // float4 index
  const int row = (int)(i >> 8);
  const int c4  = (int)(i & 255);
  const int bb  = row >> 10, t = row & 1023;
  f32x4 v;
  if (t < M_) v = ((const f32x4*)(mem + (long)t * D_))[c4];
  else        v = ((const f32x4*)(hs + (long)(bb * S_ + (t - M_)) * D_))[c4];
  ((f32x4*)xf)[i] = v;
  u16x4 ob;
  #pragma unroll
  for (int c = 0; c < 4; c++) ob[c] = f2bf(v[c]);
  ((u16x4*)xb)[i] = ob;
}

// ---------------- weight transpose fp32(KxN) -> bf16(NxK) ----------------
__global__ __launch_bounds__(256) void wtrans(const float* __restrict__ W,
                                              u16* __restrict__ WT, int K, int N) {
  __shared__ float t[32][33];
  const int n0 = blockIdx.x * 32, k0 = blockIdx.y * 32;
  const int tx = threadIdx.x, ty = threadIdx.y;
  #pragma unroll
  for (int r = 0; r < 32; r += 8)
    t[ty + r][tx] = W[(long)(k0 + ty + r) * N + n0 + tx];
  __syncthreads();
  #pragma unroll
  for (int r = 0; r < 32; r += 8)
    WT[(long)(n0 + ty + r) * K + k0 + tx] = f2bf(t[tx][ty + r]);
}

// ---------------- LayerNorm: y -> xf (fp32) + xb (bf16) ----------------
__global__ __launch_bounds__(256) void ln_k(const float* __restrict__ y,
                                            const float* __restrict__ ga,
                                            const float* __restrict__ be,
                                            float* __restrict__ xf,
                                            u16* __restrict__ xb) {
  const int row = blockIdx.x, tid = threadIdx.x;
  const f32x4 v = ((const f32x4*)(y + (long)row * D_))[tid];
  float s  = v[0] + v[1] + v[2] + v[3];
  float ss = v[0]*v[0] + v[1]*v[1] + v[2]*v[2] + v[3]*v[3];
  #pragma unroll
  for (int m = 1; m < 64; m <<= 1) { s += __shfl_xor(s, m); ss += __shfl_xor(ss, m); }
  __shared__ float sm[8];
  if ((tid & 63) == 0) { sm[tid >> 6] = s; sm[4 + (tid >> 6)] = ss; }
  __syncthreads();
  s  = sm[0] + sm[1] + sm[2] + sm[3];
  ss = sm[4] + sm[5] + sm[6] + sm[7];
  const float mu  = s * (1.0f / D_);
  const float var = ss * (1.0f / D_) - mu * mu;
  const float rs  = rsqrtf(var + 1e-12f);
  const f32x4 gg = ((const f32x4*)ga)[tid];
  const f32x4 bb = ((const f32x4*)be)[tid];
  f32x4 o; u16x4 ob;
  #pragma unroll
  for (int c = 0; c < 4; c++) { o[c] = (v[c] - mu) * rs * gg[c] + bb[c]; ob[c] = f2bf(o[c]); }
  ((f32x4*)(xf + (long)row * D_))[tid] = o;
  ((u16x4*)(xb + (long)row * D_))[tid] = ob;
}

// ---------------- copy read_out ----------------
__global__ __launch_bounds__(256) void copy_ro(const float* __restrict__ xf,
                                               float* __restrict__ dst) {
  const long i  = (long)blockIdx.x * 256 + threadIdx.x;   // float4 idx
  const int row = (int)(i >> 8);
  const int c4  = (int)(i & 255);
  const int bb  = row >> 7, t = row & 127;
  f32x4 v = ((const f32x4*)(xf + (long)(bb * T_ + t) * D_))[c4];
  ((f32x4*)dst)[i] = v;
}

// ---------------- GEMM: C = A(bf16 MxK) @ BT(bf16 NxK)^T, m97 structure ----------------
// EPI: 0=QKV scatter  1=bias+residual->f32  2=bias+gelu->bf16  3=bias+gelu->f32
// RMAP: 1 = final projector A-row remap (skip mem rows)
template <int EPI, int RMAP>
__global__ __launch_bounds__(256) void gemm_bt(const u16* __restrict__ A,
                                               const u16* __restrict__ BT,
                                               const float* __restrict__ bias0,
                                               const float* __restrict__ bias1,
                                               const float* __restrict__ bias2,
                                               const float* __restrict__ resid,
                                               float* __restrict__ of,
                                               u16* __restrict__ ob0,
                                               u16* __restrict__ ob1,
                                               u16* __restrict__ ob2,
                                               int M, int N, int K) {
  __shared__ u16 As[128 * 32];
  __shared__ u16 Bs[128 * 32];
  const int tid = threadIdx.x;
  const int l   = tid & 63;
  const int w   = tid >> 6;
  const int r16 = l & 15;
  const int g   = l >> 4;
  const int bm = blockIdx.x, bn = blockIdx.y;

  // staging coords: chunk(w)/(w+4), each lane 16B
  const int srow0 = w * 16 + (l >> 2);
  const int srow1 = srow0 + 64;
  const int scol  = (l & 3) * 8;
  long ar0 = (long)bm * 128 + srow0;
  long ar1 = (long)bm * 128 + srow1;
  if (RMAP == 1) {                       // R -> b*1024 + 128 + R%896
    int R0 = (int)ar0, R1 = (int)ar1;
    ar0 = (long)(R0 / 896) * 1024 + 128 + (R0 % 896);
    ar1 = (long)(R1 / 896) * 1024 + 128 + (R1 % 896);
  }
  const u16* Ag0 = A + ar0 * K + scol;
  const u16* Ag1 = A + ar1 * K + scol;
  const u16* Bg0 = BT + ((long)bn * 128 + srow0) * K + scol;
  const u16* Bg1 = BT + ((long)bn * 128 + srow1) * K + scol;
  u16* AsD0 = As + w * 512; u16* AsD1 = As + (w + 4) * 512;
  u16* BsD0 = Bs + w * 512; u16* BsD1 = Bs + (w + 4) * 512;

  const int wm = w >> 1, wn = w & 1;
  const int aro = (wm * 64 + r16) * 32 + g * 8;
  const int bro = (wn * 64 + r16) * 32 + g * 8;

  f32x4 acc[4][4];
  #pragma unroll
  for (int i = 0; i < 4; i++)
    #pragma unroll
    for (int j = 0; j < 4; j++) acc[i][j] = (f32x4){0.f, 0.f, 0.f, 0.f};

  for (int k0 = 0; k0 < K; k0 += 32) {
    gld16(Ag0 + k0, AsD0);
    gld16(Ag1 + k0, AsD1);
    gld16(Bg0 + k0, BsD0);
    gld16(Bg1 + k0, BsD1);
    __syncthreads();                      // vmcnt drained by compiler before barrier
    bf16x8 af[4], bfr[4];
    #pragma unroll
    for (int i = 0; i < 4; i++) af[i]  = *(const bf16x8*)&As[aro + i * 512];
    #pragma unroll
    for (int j = 0; j < 4; j++) bfr[j] = *(const bf16x8*)&Bs[bro + j * 512];
    #pragma unroll
    for (int i = 0; i < 4; i++)
      #pragma unroll
      for (int j = 0; j < 4; j++)
        acc[i][j] = __builtin_amdgcn_mfma_f32_16x16x32_bf16(af[i], bfr[j], acc[i][j], 0, 0, 0);
    __syncthreads();
  }

  // epilogue: C[row=(l>>4)*4+rr][col=l&15] per 16x16 tile (m89/m91 layout)
  #pragma unroll
  for (int i = 0; i < 4; i++) {
    const int grow0 = bm * 128 + wm * 64 + i * 16 + g * 4;
    #pragma unroll
    for (int j = 0; j < 4; j++) {
      const int gcol = bn * 128 + wn * 64 + j * 16 + r16;
      f32x4 v = acc[i][j];
      if (EPI == 0) {
        const int bb = grow0 >> 10, t0 = grow0 & 1023;
        if (gcol < 1024) {                       // Q (pre-scaled by 1/8)
          const float bi = bias0[gcol];
          const int h = gcol >> 6, d = gcol & 63;
          u16* dst = ob0 + ((long)(bb * H_ + h) * T_) * DH + d;
          #pragma unroll
          for (int rr = 0; rr < 4; rr++) dst[(long)(t0 + rr) * DH] = f2bf((v[rr] + bi) * 0.125f);
        } else if (gcol < 2048) {                // K
          const int c = gcol - 1024;
          const float bi = bias1[c];
          const int h = c >> 6, d = c & 63;
          u16* dst = ob1 + ((long)(bb * H_ + h) * T_) * DH + d;
          #pragma unroll
          for (int rr = 0; rr < 4; rr++) dst[(long)(t0 + rr) * DH] = f2bf(v[rr] + bi);
        } else {                                 // V -> transposed (bh, d, t)
          const int c = gcol - 2048;
          const float bi = bias2[c];
          const int h = c >> 6, d = c & 63;
          u16x4 pk;
          #pragma unroll
          for (int rr = 0; rr < 4; rr++) pk[rr] = f2bf(v[rr] + bi);
          *(u16x4*)(ob2 + ((long)(bb * H_ + h) * DH + d) * T_ + t0) = pk;
        }
      } else if (EPI == 1) {
        const float bi = bias0[gcol];
        #pragma unroll
        for (int rr = 0; rr < 4; rr++) {
          const long idx = (long)(grow0 + rr) * N + gcol;
          of[idx] = v[rr] + bi + resid[idx];
        }
      } else if (EPI == 2) {
        const float bi = bias0[gcol];
        #pragma unroll
        for (int rr = 0; rr < 4; rr++)
          ob0[(long)(grow0 + rr) * N + gcol] = f2bf(geluf(v[rr] + bi));
      } else {
        const float bi = bias0[gcol];
        #pragma unroll
        for (int rr = 0; rr < 4; rr++)
          of[(long)(grow0 + rr) * N + gcol] = geluf(v[rr] + bi);
      }
    }
  }
}

// ---------------- fused flash attention (v2: swapped 32x32, zero-DS hot loop) ----------------
// One wave = 32 q-rows of one (b,h). S^T = mfma_32x32x16(K, Q): col=q (lane&31),
// row=key=(reg&3)+8*(reg>>2)+4*(lane>>5) -- 16 of 32 keys lane-local, halves on
// lanes l and l+32. Row reduce = in-lane tree + v_permlane32_swap (VALU). P->bf16
// via v_cvt_pk_bf16_f32 + permlane swaps builds the PV B-frag (k=(l>>5)*8+i)
// exactly (T12). PV = mfma(V^T, P^T) K=16. No LDS, no DS ops, no barriers.
__global__ __launch_bounds__(256) void attn_k(const u16* __restrict__ qB,
                                              const u16* __restrict__ kB,
                                              const u16* __restrict__ vT,
                                              u16* __restrict__ ctx) {
  const int l   = threadIdx.x & 63, w = threadIdx.x >> 6;
  const int q31 = l & 31, hl = l >> 5;
  const int bh  = blockIdx.y, bb = bh >> 4, h = bh & 15;
  const int qbase = (blockIdx.x * 4 + w) * 32;
  const u16* qh = qB + (long)bh * T_ * DH;
  const u16* kh = kB + (long)bh * T_ * DH;
  const u16* vh = vT + (long)bh * DH * T_;

  // Q B-frags (n=q=lane&31, k=d=d0*16+hl*8+i), loaded once
  bf16x8 qf[4];
  #pragma unroll
  for (int d0 = 0; d0 < 4; d0++)
    qf[d0] = *(const bf16x8*)&qh[(qbase + q31) * DH + d0 * 16 + hl * 8];

  f32x16 ot0, ot1;
  #pragma unroll
  for (int i = 0; i < 16; i++) { ot0[i] = 0.f; ot1[i] = 0.f; }
  float m = -1e30f, lsum = 0.f;

  for (int kb0 = 0; kb0 < T_; kb0 += 32) {
    // V^T A-frags (m=d=lane&31 within tile, k=key=(hl)*8+i), issue early
    bf16x8 vf0a = *(const bf16x8*)&vh[q31 * T_ + kb0 + hl * 8];
    bf16x8 vf0b = *(const bf16x8*)&vh[q31 * T_ + kb0 + 16 + hl * 8];
    bf16x8 vf1a = *(const bf16x8*)&vh[(32 + q31) * T_ + kb0 + hl * 8];
    bf16x8 vf1b = *(const bf16x8*)&vh[(32 + q31) * T_ + kb0 + 16 + hl * 8];

    // S^T = K @ Q^T over DH=64 (4 x K=16)
    f32x16 st;
    #pragma unroll
    for (int i = 0; i < 16; i++) st[i] = 0.f;
    #pragma unroll
    for (int d0 = 0; d0 < 4; d0++) {
      bf16x8 kf = *(const bf16x8*)&kh[(kb0 + q31) * DH + d0 * 16 + hl * 8];
      st = __builtin_amdgcn_mfma_f32_32x32x16_bf16(kf, qf[d0], st, 0, 0, 0);
    }

    // row max: in-lane tree over 16, then cross-half swap (VALU) + max
    float x0 = fmaxf(st[0], st[1]),   x1 = fmaxf(st[2], st[3]);
    float x2 = fmaxf(st[4], st[5]),   x3 = fmaxf(st[6], st[7]);
    float x4 = fmaxf(st[8], st[9]),   x5 = fmaxf(st[10], st[11]);
    float x6 = fmaxf(st[12], st[13]), x7 = fmaxf(st[14], st[15]);
    float pm = fmaxf(fmaxf(fmaxf(x0, x1), fmaxf(x2, x3)),
                     fmaxf(fmaxf(x4, x5), fmaxf(x6, x7)));
    {
      float a = pm, b = pm;
      asm("v_permlane32_swap_b32 %0, %1" : "+v"(a), "+v"(b));
      pm = fmaxf(a, b);
    }

    // defer-max (T13, THR=8): only rescale when the running max grew enough
    if (!__all(pm <= m + 8.0f)) {
      const float nm = fmaxf(m, pm);
      const float sc = __expf(m - nm);
      m = nm;
      lsum *= sc;
      #pragma unroll
      for (int i = 0; i < 16; i++) { ot0[i] *= sc; ot1[i] *= sc; }
    }

    // P = exp(S - m), row sum (in-lane + swap)
    float p[16], sum = 0.f;
    #pragma unroll
    for (int i = 0; i < 16; i++) { p[i] = __expf(st[i] - m); sum += p[i]; }
    {
      float a = sum, b = sum;
      asm("v_permlane32_swap_b32 %0, %1" : "+v"(a), "+v"(b));
      sum = a + b;
    }
    lsum += sum;

    // pack P -> bf16 B-frags: pk[i] = cvt_pk(p[2i], p[2i+1]); swap pairs (T12)
    u32 pk[8];
    #pragma unroll
    for (int i = 0; i < 8; i++)
      asm("v_cvt_pk_bf16_f32 %0, %1, %2" : "=v"(pk[i]) : "v"(p[2 * i]), "v"(p[2 * i + 1]));
    asm("v_permlane32_swap_b32 %0, %1" : "+v"(pk[0]), "+v"(pk[2]));
    asm("v_permlane32_swap_b32 %0, %1" : "+v"(pk[1]), "+v"(pk[3]));
    asm("v_permlane32_swap_b32 %0, %1" : "+v"(pk[4]), "+v"(pk[6]));
    asm("v_permlane32_swap_b32 %0, %1" : "+v"(pk[5]), "+v"(pk[7]));
    union { u32 u[4]; bf16x8 v; } f1, f2;
    f1.u[0] = pk[0]; f1.u[1] = pk[1]; f1.u[2] = pk[2]; f1.u[3] = pk[3];
    f2.u[0] = pk[4]; f2.u[1] = pk[5]; f2.u[2] = pk[6]; f2.u[3] = pk[7];

    // O^T += V^T @ P^T  (keys 0-15 then 16-31)
    ot0 = __builtin_amdgcn_mfma_f32_32x32x16_bf16(vf0a, f1.v, ot0, 0, 0, 0);
    ot0 = __builtin_amdgcn_mfma_f32_32x32x16_bf16(vf0b, f2.v, ot0, 0, 0, 0);
    ot1 = __builtin_amdgcn_mfma_f32_32x32x16_bf16(vf1a, f1.v, ot1, 0, 0, 0);
    ot1 = __builtin_amdgcn_mfma_f32_32x32x16_bf16(vf1b, f2.v, ot1, 0, 0, 0);
  }

  const float inv = 1.0f / lsum;
  u16* dst = ctx + ((long)(bb * T_ + qbase + q31)) * D_ + h * DH;
  #pragma unroll
  for (int rg = 0; rg < 4; rg++) {
    u16x4 o0, o1;
    #pragma unroll
    for (int r = 0; r < 4; r++) {
      o0[r] = f2bf(ot0[rg * 4 + r] * inv);
      o1[r] = f2bf(ot1[rg * 4 + r] * inv);
    }
    const int d0 = rg * 8 + hl * 4;        // d=(reg&3)+8*(reg>>2)+4*hl
    *(u16x4*)(dst + d0) = o0;
    *(u16x4*)(dst + 32 + d0) = o1;
  }
}

// ---------------- host ----------------
extern "C" void kernel_launch(void* const* d_in, const int* in_sizes, int n_in,
                              void* d_out, int out_size, void* d_ws, size_t ws_size,
                              hipStream_t stream) {
  const float* hs  = (const float*)d_in[0];
  const float* mem = (const float*)d_in[1];
  const float* Wq  = (const float*)d_in[2];
  const float* bq  = (const float*)d_in[3];
  const float* Wk  = (const float*)d_in[4];
  const float* bk  = (const float*)d_in[5];
  const float* Wv  = (const float*)d_in[6];
  const float* bv  = (const float*)d_in[7];
  const float* Wo  = (const float*)d_in[8];
  const float* bo  = (const float*)d_in[9];
  const float* g1  = (const float*)d_in[10];
  const float* be1 = (const float*)d_in[11];
  const float* Wm  = (const float*)d_in[12];
  const float* bm  = (const float*)d_in[13];
  const float* Wr  = (const float*)d_in[14];
  const float* br  = (const float*)d_in[15];
  const float* g2  = (const float*)d_in[16];
  const float* be2 = (const float*)d_in[17];
  const float* Wp  = (const float*)d_in[18];
  const float* bp  = (const float*)d_in[19];
  float* out = (float*)d_out;

  char* ws = (char*)d_ws;
  float* xf  = (float*)(ws + 0);                 // 16 MB
  u16*   xb  = (u16*)  (ws + 16777216);          //  8 MB
  float* yb  = (float*)(ws + 25165824);          // 16 MB
  u16*   qb  = (u16*)  (ws + 41943040);          //  8 MB
  u16*   kb2 = (u16*)  (ws + 50331648);          //  8 MB
  u16*   vtb = (u16*)  (ws + 58720256);          //  8 MB
  u16*   ctx = (u16*)  (ws + 67108864);          //  8 MB
  u16*   ib  = qb;                               // 32 MB alias (qkv/ctx dead when live)
  u16*   WTqkv = (u16*)(ws + 75497472);          // 12 MB
  u16*   WTo   = (u16*)(ws + 88080384);          //  4 MB
  u16*   WTm   = (u16*)(ws + 92274688);          // 16 MB
  u16*   WTr   = (u16*)(ws + 109051904);         // 16 MB
  u16*   WTp   = (u16*)(ws + 125829120);         //  8 MB  (total 128 MB)

  const dim3 blk(256);
  const dim3 tb(32, 8);

  build_x<<<dim3(4096), blk, 0, stream>>>(hs, mem, xf, xb);

  for (int l = 0; l < L_; l++) {
    wtrans<<<dim3(32, 32), tb, 0, stream>>>(Wq + (long)l * D_ * D_, WTqkv + (long)l * 3072 * 1024, 1024, 1024);
    wtrans<<<dim3(32, 32), tb, 0, stream>>>(Wk + (long)l * D_ * D_, WTqkv + (long)l * 3072 * 1024 + 1024 * 1024, 1024, 1024);
    wtrans<<<dim3(32, 32), tb, 0, stream>>>(Wv + (long)l * D_ * D_, WTqkv + (long)l * 3072 * 1024 + 2048 * 1024, 1024, 1024);
    wtrans<<<dim3(32, 32), tb, 0, stream>>>(Wo + (long)l * D_ * D_, WTo + (long)l * 1024 * 1024, 1024, 1024);
    wtrans<<<dim3(128, 32), tb, 0, stream>>>(Wm + (long)l * D_ * I_, WTm + (long)l * 4096 * 1024, 1024, 4096);
    wtrans<<<dim3(32, 128), tb, 0, stream>>>(Wr + (long)l * I_ * D_, WTr + (long)l * 4096 * 1024, 4096, 1024);
  }
  wtrans<<<dim3(128, 32), tb, 0, stream>>>(Wp, WTp, 1024, 4096);

  for (int l = 0; l < L_; l++) {
    // fused QKV
    gemm_bt<0, 0><<<dim3(32, 24), blk, 0, stream>>>(xb, WTqkv + (long)l * 3072 * 1024,
        bq + l * D_, bk + l * D_, bv + l * D_, nullptr,
        nullptr, qb, kb2, vtb, NROW, 3072, 1024);
    // attention (v2)
    attn_k<<<dim3(8, 64), blk, 0, stream>>>(qb, kb2, vtb, ctx);
    // O projection + bias + residual
    gemm_bt<1, 0><<<dim3(32, 8), blk, 0, stream>>>(ctx, WTo + (long)l * 1024 * 1024,
        bo + l * D_, nullptr, nullptr, xf,
        yb, nullptr, nullptr, nullptr, NROW, 1024, 1024);
    ln_k<<<dim3(4096), blk, 0, stream>>>(yb, g1 + l * D_, be1 + l * D_, xf, xb);
    // FFN1 + gelu -> bf16
    gemm_bt<2, 0><<<dim3(32, 32), blk, 0, stream>>>(xb, WTm + (long)l * 4096 * 1024,
        bm + l * I_, nullptr, nullptr, nullptr,
        nullptr, ib, nullptr, nullptr, NROW, 4096, 1024);
    // FFN2 + bias + residual
    gemm_bt<1, 0><<<dim3(32, 8), blk, 0, stream>>>(ib, WTr + (long)l * 4096 * 1024,
        br + l * D_, nullptr, nullptr, xf,
        yb, nullptr, nullptr, nullptr, NROW, 1024, 4096);
    ln_k<<<dim3(4096), blk, 0, stream>>>(yb, g2 + l * D_, be2 + l * D_, xf, xb);
  }

  // final projector on non-mem rows (M=3584=28*128), + gelu -> f32 out
  gemm_bt<3, 1><<<dim3(28, 32), blk, 0, stream>>>(xb, WTp,
      bp, nullptr, nullptr, nullptr,
      out, nullptr, nullptr, nullptr, 3584, 4096, 1024);
  // read_out = x[:, :M]
  copy_ro<<<dim3(512), blk, 0, stream>>>(xf, out + 14680064);
}

// Round 6
// 844.626 us; speedup vs baseline: 1.2077x; 1.0812x over previous
//
#include <hip/hip_runtime.h>
#include <math.h>

// ---------------- problem constants ----------------
#define B_    4
#define S_    896
#define D_    1024
#define H_    16
#define I_    4096
#define OUT_  4096
#define L_    2
#define M_    128
#define T_    1024           // M_ + S_
#define NROW  4096           // B_ * T_
#define DH    64             // D_/H_

typedef unsigned short u16;
typedef unsigned int   u32;
typedef float  f32x4  __attribute__((ext_vector_type(4)));
typedef float  f32x16 __attribute__((ext_vector_type(16)));
typedef __bf16 bf16x8 __attribute__((ext_vector_type(8)));
typedef u16    u16x2  __attribute__((ext_vector_type(2)));
typedef u16    u16x4  __attribute__((ext_vector_type(4)));

typedef __attribute__((address_space(1))) const void gvoid;
typedef __attribute__((address_space(3))) void       lvoid;

__device__ __forceinline__ u16 f2bf(float f) {
  u32 u = __builtin_bit_cast(u32, f);
  u = (u + 0x7fffu + ((u >> 16) & 1u)) >> 16;   // RNE; inputs are tame (no inf/nan)
  return (u16)u;
}
__device__ __forceinline__ float geluf(float v) {
  return 0.5f * v * (1.0f + erff(v * 0.70710678118654752f));
}
__device__ __forceinline__ void gld16(const void* g, void* l) {
  // async global->LDS, dest = wave-uniform base + lane*16 (linear, no swizzle)
  __builtin_amdgcn_global_load_lds((gvoid*)g, (lvoid*)l, 16, 0, 0);
}

// ---------------- build x = concat(mem, hidden) ----------------
__global__ __launch_bounds__(256) void build_x(const float* __restrict__ hs,
                                               const float* __restrict__ mem,
                                               float* __restrict__ xf,
                                               u16* __restrict__ xb) {
  const long i  = (long)blockIdx.x * 256 + threadIdx.x;   // float4 index
  const int row = (int)(i >> 8);
  const int c4  = (int)(i & 255);
  const int bb  = row >> 10, t = row & 1023;
  f32x4 v;
  if (t < M_) v = ((const f32x4*)(mem + (long)t * D_))[c4];
  else        v = ((const f32x4*)(hs + (long)(bb * S_ + (t - M_)) * D_))[c4];
  ((f32x4*)xf)[i] = v;
  u16x4 ob;
  #pragma unroll
  for (int c = 0; c < 4; c++) ob[c] = f2bf(v[c]);
  ((u16x4*)xb)[i] = ob;
}

// ---------------- weight transpose fp32(KxN) -> bf16(NxK) ----------------
__global__ __launch_bounds__(256) void wtrans(const float* __restrict__ W,
                                              u16* __restrict__ WT, int K, int N) {
  __shared__ float t[32][33];
  const int n0 = blockIdx.x * 32, k0 = blockIdx.y * 32;
  const int tx = threadIdx.x, ty = threadIdx.y;
  #pragma unroll
  for (int r = 0; r < 32; r += 8)
    t[ty + r][tx] = W[(long)(k0 + ty + r) * N + n0 + tx];
  __syncthreads();
  #pragma unroll
  for (int r = 0; r < 32; r += 8)
    WT[(long)(n0 + ty + r) * K + k0 + tx] = f2bf(t[tx][ty + r]);
}

// ---------------- LayerNorm over summed split-K partials + bias + residual ----------------
// y = p0+p1+p2 + bias + resid; LN(y) -> xf (f32) + xb (bf16). p0/p1/p2 MUST be
// contiguous 16MB slabs (epilogue writes of + z*M*N) -- R4's bug was violating this.
__global__ __launch_bounds__(256) void lnred_k(const float* __restrict__ p0,
                                               const float* __restrict__ p1,
                                               const float* __restrict__ p2,
                                               const float* __restrict__ bias,
                                               const float* __restrict__ resid,
                                               const float* __restrict__ ga,
                                               const float* __restrict__ be,
                                               float* __restrict__ xf,
                                               u16* __restrict__ xb) {
  const int row = blockIdx.x, tid = threadIdx.x;
  const long ro = (long)row * D_;
  f32x4 v = ((const f32x4*)(p0 + ro))[tid];
  const f32x4 v1 = ((const f32x4*)(p1 + ro))[tid];
  const f32x4 v2 = ((const f32x4*)(p2 + ro))[tid];
  const f32x4 bi = ((const f32x4*)bias)[tid];
  const f32x4 rs4 = ((const f32x4*)(resid + ro))[tid];
  #pragma unroll
  for (int c = 0; c < 4; c++) v[c] = v[c] + v1[c] + v2[c] + bi[c] + rs4[c];
  float s  = v[0] + v[1] + v[2] + v[3];
  float ss = v[0]*v[0] + v[1]*v[1] + v[2]*v[2] + v[3]*v[3];
  #pragma unroll
  for (int m = 1; m < 64; m <<= 1) { s += __shfl_xor(s, m); ss += __shfl_xor(ss, m); }
  __shared__ float sm[8];
  if ((tid & 63) == 0) { sm[tid >> 6] = s; sm[4 + (tid >> 6)] = ss; }
  __syncthreads();
  s  = sm[0] + sm[1] + sm[2] + sm[3];
  ss = sm[4] + sm[5] + sm[6] + sm[7];
  const float mu  = s * (1.0f / D_);
  const float var = ss * (1.0f / D_) - mu * mu;
  const float rs  = rsqrtf(var + 1e-12f);
  const f32x4 gg = ((const f32x4*)ga)[tid];
  const f32x4 bb = ((const f32x4*)be)[tid];
  f32x4 o; u16x4 ob;
  #pragma unroll
  for (int c = 0; c < 4; c++) { o[c] = (v[c] - mu) * rs * gg[c] + bb[c]; ob[c] = f2bf(o[c]); }
  ((f32x4*)(xf + ro))[tid] = o;
  ((u16x4*)(xb + ro))[tid] = ob;
}

// ---------------- copy read_out ----------------
__global__ __launch_bounds__(256) void copy_ro(const float* __restrict__ xf,
                                               float* __restrict__ dst) {
  const long i  = (long)blockIdx.x * 256 + threadIdx.x;   // float4 idx
  const int row = (int)(i >> 8);
  const int c4  = (int)(i & 255);
  const int bb  = row >> 7, t = row & 127;
  f32x4 v = ((const f32x4*)(xf + (long)(bb * T_ + t) * D_))[c4];
  ((f32x4*)dst)[i] = v;
}

// ---------------- GEMM: C = A(bf16 MxK) @ BT(bf16 NxK)^T, m97 structure ----------------
// EPI: 0=QKV scatter  2=bias+gelu->bf16  3=bias+gelu->f32  4=split-K partial f32
// RMAP: 1 = final projector A-row remap (skip mem rows)
// EPI=4: blockIdx.z selects K-chunk [z*KC, min((z+1)*KC,K)); partial z goes to
// of + z*M*N (CONTIGUOUS slabs). Raises blocks/CU for skinny-N GEMMs.
template <int EPI, int RMAP>
__global__ __launch_bounds__(256) void gemm_bt(const u16* __restrict__ A,
                                               const u16* __restrict__ BT,
                                               const float* __restrict__ bias0,
                                               const float* __restrict__ bias1,
                                               const float* __restrict__ bias2,
                                               float* __restrict__ of,
                                               u16* __restrict__ ob0,
                                               u16* __restrict__ ob1,
                                               u16* __restrict__ ob2,
                                               int M, int N, int K, int KC) {
  __shared__ u16 As[128 * 32];
  __shared__ u16 Bs[128 * 32];
  const int tid = threadIdx.x;
  const int l   = tid & 63;
  const int w   = tid >> 6;
  const int r16 = l & 15;
  const int g   = l >> 4;
  const int bm = blockIdx.x, bn = blockIdx.y;

  const int kstart = (EPI == 4) ? blockIdx.z * KC : 0;
  const int klen   = (EPI == 4) ? min(KC, K - kstart) : K;

  // staging coords: chunk(w)/(w+4), each lane 16B
  const int srow0 = w * 16 + (l >> 2);
  const int srow1 = srow0 + 64;
  const int scol  = (l & 3) * 8;
  long ar0 = (long)bm * 128 + srow0;
  long ar1 = (long)bm * 128 + srow1;
  if (RMAP == 1) {                       // R -> b*1024 + 128 + R%896
    int R0 = (int)ar0, R1 = (int)ar1;
    ar0 = (long)(R0 / 896) * 1024 + 128 + (R0 % 896);
    ar1 = (long)(R1 / 896) * 1024 + 128 + (R1 % 896);
  }
  const u16* Ag0 = A + ar0 * K + kstart + scol;
  const u16* Ag1 = A + ar1 * K + kstart + scol;
  const u16* Bg0 = BT + ((long)bn * 128 + srow0) * K + kstart + scol;
  const u16* Bg1 = BT + ((long)bn * 128 + srow1) * K + kstart + scol;
  u16* AsD0 = As + w * 512; u16* AsD1 = As + (w + 4) * 512;
  u16* BsD0 = Bs + w * 512; u16* BsD1 = Bs + (w + 4) * 512;

  const int wm = w >> 1, wn = w & 1;
  const int aro = (wm * 64 + r16) * 32 + g * 8;
  const int bro = (wn * 64 + r16) * 32 + g * 8;

  f32x4 acc[4][4];
  #pragma unroll
  for (int i = 0; i < 4; i++)
    #pragma unroll
    for (int j = 0; j < 4; j++) acc[i][j] = (f32x4){0.f, 0.f, 0.f, 0.f};

  for (int k0 = 0; k0 < klen; k0 += 32) {
    gld16(Ag0 + k0, AsD0);
    gld16(Ag1 + k0, AsD1);
    gld16(Bg0 + k0, BsD0);
    gld16(Bg1 + k0, BsD1);
    __syncthreads();                      // vmcnt drained by compiler before barrier
    bf16x8 af[4], bfr[4];
    #pragma unroll
    for (int i = 0; i < 4; i++) af[i]  = *(const bf16x8*)&As[aro + i * 512];
    #pragma unroll
    for (int j = 0; j < 4; j++) bfr[j] = *(const bf16x8*)&Bs[bro + j * 512];
    #pragma unroll
    for (int i = 0; i < 4; i++)
      #pragma unroll
      for (int j = 0; j < 4; j++)
        acc[i][j] = __builtin_amdgcn_mfma_f32_16x16x32_bf16(af[i], bfr[j], acc[i][j], 0, 0, 0);
    __syncthreads();
  }

  // epilogue: C[row=(l>>4)*4+rr][col=l&15] per 16x16 tile (m89/m91 layout)
  float* pof = (EPI == 4) ? of + (long)blockIdx.z * ((long)M * N) : of;
  #pragma unroll
  for (int i = 0; i < 4; i++) {
    const int grow0 = bm * 128 + wm * 64 + i * 16 + g * 4;
    #pragma unroll
    for (int j = 0; j < 4; j++) {
      const int gcol = bn * 128 + wn * 64 + j * 16 + r16;
      f32x4 v = acc[i][j];
      if (EPI == 0) {
        const int bb = grow0 >> 10, t0 = grow0 & 1023;
        if (gcol < 1024) {                       // Q (pre-scaled by 1/8)
          const float bi = bias0[gcol];
          const int h = gcol >> 6, d = gcol & 63;
          u16* dst = ob0 + ((long)(bb * H_ + h) * T_) * DH + d;
          #pragma unroll
          for (int rr = 0; rr < 4; rr++) dst[(long)(t0 + rr) * DH] = f2bf((v[rr] + bi) * 0.125f);
        } else if (gcol < 2048) {                // K
          const int c = gcol - 1024;
          const float bi = bias1[c];
          const int h = c >> 6, d = c & 63;
          u16* dst = ob1 + ((long)(bb * H_ + h) * T_) * DH + d;
          #pragma unroll
          for (int rr = 0; rr < 4; rr++) dst[(long)(t0 + rr) * DH] = f2bf(v[rr] + bi);
        } else {                                 // V -> transposed (bh, d, t)
          const int c = gcol - 2048;
          const float bi = bias2[c];
          const int h = c >> 6, d = c & 63;
          u16x4 pk;
          #pragma unroll
          for (int rr = 0; rr < 4; rr++) pk[rr] = f2bf(v[rr] + bi);
          *(u16x4*)(ob2 + ((long)(bb * H_ + h) * DH + d) * T_ + t0) = pk;
        }
      } else if (EPI == 2) {
        const float bi = bias0[gcol];
        #pragma unroll
        for (int rr = 0; rr < 4; rr++)
          ob0[(long)(grow0 + rr) * N + gcol] = f2bf(geluf(v[rr] + bi));
      } else if (EPI == 3) {
        const float bi = bias0[gcol];
        #pragma unroll
        for (int rr = 0; rr < 4; rr++)
          of[(long)(grow0 + rr) * N + gcol] = geluf(v[rr] + bi);
      } else {                                   // EPI==4: raw partial
        #pragma unroll
        for (int rr = 0; rr < 4; rr++)
          pof[(long)(grow0 + rr) * N + gcol] = v[rr];
      }
    }
  }
}

// ---------------- fused flash attention (v2: swapped 32x32, zero-DS hot loop) ----------------
// One wave = 32 q-rows of one (b,h). S^T = mfma_32x32x16(K, Q): col=q (lane&31),
// row=key=(reg&3)+8*(reg>>2)+4*(lane>>5) -- 16 of 32 keys lane-local, halves on
// lanes l and l+32. Row reduce = in-lane tree + v_permlane32_swap (VALU). P->bf16
// via v_cvt_pk_bf16_f32 + permlane swaps builds the PV B-frag (k=(l>>5)*8+i)
// exactly (T12). PV = mfma(V^T, P^T) K=16. No LDS, no DS ops, no barriers.
__global__ __launch_bounds__(256) void attn_k(const u16* __restrict__ qB,
                                              const u16* __restrict__ kB,
                                              const u16* __restrict__ vT,
                                              u16* __restrict__ ctx) {
  const int l   = threadIdx.x & 63, w = threadIdx.x >> 6;
  const int q31 = l & 31, hl = l >> 5;
  const int bh  = blockIdx.y, bb = bh >> 4, h = bh & 15;
  const int qbase = (blockIdx.x * 4 + w) * 32;
  const u16* qh = qB + (long)bh * T_ * DH;
  const u16* kh = kB + (long)bh * T_ * DH;
  const u16* vh = vT + (long)bh * DH * T_;

  // Q B-frags (n=q=lane&31, k=d=d0*16+hl*8+i), loaded once
  bf16x8 qf[4];
  #pragma unroll
  for (int d0 = 0; d0 < 4; d0++)
    qf[d0] = *(const bf16x8*)&qh[(qbase + q31) * DH + d0 * 16 + hl * 8];

  f32x16 ot0, ot1;
  #pragma unroll
  for (int i = 0; i < 16; i++) { ot0[i] = 0.f; ot1[i] = 0.f; }
  float m = -1e30f, lsum = 0.f;

  for (int kb0 = 0; kb0 < T_; kb0 += 32) {
    // V^T A-frags (m=d=lane&31 within tile, k=key=(hl)*8+i), issue early
    bf16x8 vf0a = *(const bf16x8*)&vh[q31 * T_ + kb0 + hl * 8];
    bf16x8 vf0b = *(const bf16x8*)&vh[q31 * T_ + kb0 + 16 + hl * 8];
    bf16x8 vf1a = *(const bf16x8*)&vh[(32 + q31) * T_ + kb0 + hl * 8];
    bf16x8 vf1b = *(const bf16x8*)&vh[(32 + q31) * T_ + kb0 + 16 + hl * 8];

    // S^T = K @ Q^T over DH=64 (4 x K=16)
    f32x16 st;
    #pragma unroll
    for (int i = 0; i < 16; i++) st[i] = 0.f;
    #pragma unroll
    for (int d0 = 0; d0 < 4; d0++) {
      bf16x8 kf = *(const bf16x8*)&kh[(kb0 + q31) * DH + d0 * 16 + hl * 8];
      st = __builtin_amdgcn_mfma_f32_32x32x16_bf16(kf, qf[d0], st, 0, 0, 0);
    }

    // row max: in-lane tree over 16, then cross-half swap (VALU) + max
    float x0 = fmaxf(st[0], st[1]),   x1 = fmaxf(st[2], st[3]);
    float x2 = fmaxf(st[4], st[5]),   x3 = fmaxf(st[6], st[7]);
    float x4 = fmaxf(st[8], st[9]),   x5 = fmaxf(st[10], st[11]);
    float x6 = fmaxf(st[12], st[13]), x7 = fmaxf(st[14], st[15]);
    float pm = fmaxf(fmaxf(fmaxf(x0, x1), fmaxf(x2, x3)),
                     fmaxf(fmaxf(x4, x5), fmaxf(x6, x7)));
    {
      float a = pm, b = pm;
      asm("v_permlane32_swap_b32 %0, %1" : "+v"(a), "+v"(b));
      pm = fmaxf(a, b);
    }

    // defer-max (T13, THR=8): only rescale when the running max grew enough
    if (!__all(pm <= m + 8.0f)) {
      const float nm = fmaxf(m, pm);
      const float sc = __expf(m - nm);
      m = nm;
      lsum *= sc;
      #pragma unroll
      for (int i = 0; i < 16; i++) { ot0[i] *= sc; ot1[i] *= sc; }
    }

    // P = exp(S - m), row sum (in-lane + swap)
    float p[16], sum = 0.f;
    #pragma unroll
    for (int i = 0; i < 16; i++) { p[i] = __expf(st[i] - m); sum += p[i]; }
    {
      float a = sum, b = sum;
      asm("v_permlane32_swap_b32 %0, %1" : "+v"(a), "+v"(b));
      sum = a + b;
    }
    lsum += sum;

    // pack P -> bf16 B-frags: pk[i] = cvt_pk(p[2i], p[2i+1]); swap pairs (T12)
    u32 pk[8];
    #pragma unroll
    for (int i = 0; i < 8; i++)
      asm("v_cvt_pk_bf16_f32 %0, %1, %2" : "=v"(pk[i]) : "v"(p[2 * i]), "v"(p[2 * i + 1]));
    asm("v_permlane32_swap_b32 %0, %1" : "+v"(pk[0]), "+v"(pk[2]));
    asm("v_permlane32_swap_b32 %0, %1" : "+v"(pk[1]), "+v"(pk[3]));
    asm("v_permlane32_swap_b32 %0, %1" : "+v"(pk[4]), "+v"(pk[6]));
    asm("v_permlane32_swap_b32 %0, %1" : "+v"(pk[5]), "+v"(pk[7]));
    union { u32 u[4]; bf16x8 v; } f1, f2;
    f1.u[0] = pk[0]; f1.u[1] = pk[1]; f1.u[2] = pk[2]; f1.u[3] = pk[3];
    f2.u[0] = pk[4]; f2.u[1] = pk[5]; f2.u[2] = pk[6]; f2.u[3] = pk[7];

    // O^T += V^T @ P^T  (keys 0-15 then 16-31)
    ot0 = __builtin_amdgcn_mfma_f32_32x32x16_bf16(vf0a, f1.v, ot0, 0, 0, 0);
    ot0 = __builtin_amdgcn_mfma_f32_32x32x16_bf16(vf0b, f2.v, ot0, 0, 0, 0);
    ot1 = __builtin_amdgcn_mfma_f32_32x32x16_bf16(vf1a, f1.v, ot1, 0, 0, 0);
    ot1 = __builtin_amdgcn_mfma_f32_32x32x16_bf16(vf1b, f2.v, ot1, 0, 0, 0);
  }

  const float inv = 1.0f / lsum;
  u16* dst = ctx + ((long)(bb * T_ + qbase + q31)) * D_ + h * DH;
  #pragma unroll
  for (int rg = 0; rg < 4; rg++) {
    u16x4 o0, o1;
    #pragma unroll
    for (int r = 0; r < 4; r++) {
      o0[r] = f2bf(ot0[rg * 4 + r] * inv);
      o1[r] = f2bf(ot1[rg * 4 + r] * inv);
    }
    const int d0 = rg * 8 + hl * 4;        // d=(reg&3)+8*(reg>>2)+4*hl
    *(u16x4*)(dst + d0) = o0;
    *(u16x4*)(dst + 32 + d0) = o1;
  }
}

// ---------------- host ----------------
extern "C" void kernel_launch(void* const* d_in, const int* in_sizes, int n_in,
                              void* d_out, int out_size, void* d_ws, size_t ws_size,
                              hipStream_t stream) {
  const float* hs  = (const float*)d_in[0];
  const float* mem = (const float*)d_in[1];
  const float* Wq  = (const float*)d_in[2];
  const float* bq  = (const float*)d_in[3];
  const float* Wk  = (const float*)d_in[4];
  const float* bk  = (const float*)d_in[5];
  const float* Wv  = (const float*)d_in[6];
  const float* bv  = (const float*)d_in[7];
  const float* Wo  = (const float*)d_in[8];
  const float* bo  = (const float*)d_in[9];
  const float* g1  = (const float*)d_in[10];
  const float* be1 = (const float*)d_in[11];
  const float* Wm  = (const float*)d_in[12];
  const float* bm  = (const float*)d_in[13];
  const float* Wr  = (const float*)d_in[14];
  const float* br  = (const float*)d_in[15];
  const float* g2  = (const float*)d_in[16];
  const float* be2 = (const float*)d_in[17];
  const float* Wp  = (const float*)d_in[18];
  const float* bp  = (const float*)d_in[19];
  float* out = (float*)d_out;

  // ---- workspace map (128 MB; partials CONTIGUOUS — the R4 fix) ----
  char* ws = (char*)d_ws;
  float* xf  = (float*)(ws + 0);                 // 16 MB  [  0, 16M)
  u16*   xb  = (u16*)  (ws + 16777216);          //  8 MB  [ 16, 24M)
  float* p0  = (float*)(ws + 25165824);          // 16 MB  [ 24, 40M)  split-K partial 0
  float* p1  = (float*)(ws + 41943040);          // 16 MB  [ 40, 56M)  partial 1 (=p0+M*N)
  float* p2  = (float*)(ws + 58720256);          // 16 MB  [ 56, 72M)  partial 2
  u16*   qb  = (u16*)  (ws + 75497472);          //  8 MB  [ 72, 80M)
  u16*   kb2 = (u16*)  (ws + 83886080);          //  8 MB  [ 80, 88M)
  u16*   vtb = (u16*)  (ws + 92274688);          //  8 MB  [ 88, 96M)
  u16*   ctx = (u16*)  (ws + 100663296);         //  8 MB  [ 96,104M)
  u16*   ib  = qb;                               // 32 MB alias [72,104M) (qkv/ctx dead)
  // per-layer weight arena [104,128M): reused each layer
  u16*   WTqkv = (u16*)(ws + 109051904);         //  6 MB  [104,110M)
  u16*   WTo   = (u16*)(ws + 115343360);         //  2 MB  [110,112M)
  u16*   WTm   = (u16*)(ws + 117440512);         //  8 MB  [112,120M)
  u16*   WTr   = (u16*)(ws + 125829120);         //  8 MB  [120,128M)
  u16*   WTp   = WTqkv;                          //  8 MB  [104,112M) after layer loop

  const dim3 blk(256);
  const dim3 tb(32, 8);

  build_x<<<dim3(4096), blk, 0, stream>>>(hs, mem, xf, xb);

  for (int l = 0; l < L_; l++) {
    // transpose this layer's weights into the arena
    wtrans<<<dim3(32, 32), tb, 0, stream>>>(Wq + (long)l * D_ * D_, WTqkv, 1024, 1024);
    wtrans<<<dim3(32, 32), tb, 0, stream>>>(Wk + (long)l * D_ * D_, WTqkv + 1024 * 1024, 1024, 1024);
    wtrans<<<dim3(32, 32), tb, 0, stream>>>(Wv + (long)l * D_ * D_, WTqkv + 2048 * 1024, 1024, 1024);
    wtrans<<<dim3(32, 32), tb, 0, stream>>>(Wo + (long)l * D_ * D_, WTo, 1024, 1024);
    wtrans<<<dim3(128, 32), tb, 0, stream>>>(Wm + (long)l * D_ * I_, WTm, 1024, 4096);
    wtrans<<<dim3(32, 128), tb, 0, stream>>>(Wr + (long)l * I_ * D_, WTr, 4096, 1024);

    // fused QKV (768 blocks = 3/CU)
    gemm_bt<0, 0><<<dim3(32, 24), blk, 0, stream>>>(xb, WTqkv,
        bq + l * D_, bk + l * D_, bv + l * D_,
        nullptr, qb, kb2, vtb, NROW, 3072, 1024, 0);
    // attention
    attn_k<<<dim3(8, 64), blk, 0, stream>>>(qb, kb2, vtb, ctx);
    // O projection, split-K=3 (KC=352: chunks 352/352/320; 768 blocks = 3/CU)
    gemm_bt<4, 0><<<dim3(32, 8, 3), blk, 0, stream>>>(ctx, WTo,
        nullptr, nullptr, nullptr,
        p0, nullptr, nullptr, nullptr, NROW, 1024, 1024, 352);
    lnred_k<<<dim3(4096), blk, 0, stream>>>(p0, p1, p2, bo + l * D_, xf,
        g1 + l * D_, be1 + l * D_, xf, xb);
    // FFN1 + gelu -> bf16 (1024 blocks = 4/CU)
    gemm_bt<2, 0><<<dim3(32, 32), blk, 0, stream>>>(xb, WTm,
        bm + l * I_, nullptr, nullptr,
        nullptr, ib, nullptr, nullptr, NROW, 4096, 1024, 0);
    // FFN2, split-K=3 (KC=1376: chunks 1376/1376/1344; 768 blocks = 3/CU)
    gemm_bt<4, 0><<<dim3(32, 8, 3), blk, 0, stream>>>(ib, WTr,
        nullptr, nullptr, nullptr,
        p0, nullptr, nullptr, nullptr, NROW, 1024, 4096, 1376);
    lnred_k<<<dim3(4096), blk, 0, stream>>>(p0, p1, p2, br + l * D_, xf,
        g2 + l * D_, be2 + l * D_, xf, xb);
  }

  // final projector on non-mem rows (M=3584=28*128), + gelu -> f32 out
  wtrans<<<dim3(128, 32), tb, 0, stream>>>(Wp, WTp, 1024, 4096);
  gemm_bt<3, 1><<<dim3(28, 32), blk, 0, stream>>>(xb, WTp,
      bp, nullptr, nullptr,
      out, nullptr, nullptr, nullptr, 3584, 4096, 1024, 0);
  // read_out = x[:, :M]
  copy_ro<<<dim3(512), blk, 0, stream>>>(xf, out + 14680064);
}

// Round 7
// 809.833 us; speedup vs baseline: 1.2596x; 1.0430x over previous
//
#include <hip/hip_runtime.h>
#include <math.h>

// ---------------- problem constants ----------------
#define B_    4
#define S_    896
#define D_    1024
#define H_    16
#define I_    4096
#define OUT_  4096
#define L_    2
#define M_    128
#define T_    1024           // M_ + S_
#define NROW  4096           // B_ * T_
#define DH    64             // D_/H_

typedef unsigned short u16;
typedef unsigned int   u32;
typedef float  f32x4  __attribute__((ext_vector_type(4)));
typedef float  f32x16 __attribute__((ext_vector_type(16)));
typedef __bf16 bf16x8 __attribute__((ext_vector_type(8)));
typedef u16    u16x2  __attribute__((ext_vector_type(2)));
typedef u16    u16x4  __attribute__((ext_vector_type(4)));

typedef __attribute__((address_space(1))) const void gvoid;
typedef __attribute__((address_space(3))) void       lvoid;

__device__ __forceinline__ u16 f2bf(float f) {
  u32 u = __builtin_bit_cast(u32, f);
  u = (u + 0x7fffu + ((u >> 16) & 1u)) >> 16;   // RNE; inputs are tame (no inf/nan)
  return (u16)u;
}
__device__ __forceinline__ float geluf(float v) {
  return 0.5f * v * (1.0f + erff(v * 0.70710678118654752f));
}
__device__ __forceinline__ void gld16(const void* g, void* l) {
  // async global->LDS, dest = wave-uniform base + lane*16 (linear, no swizzle)
  __builtin_amdgcn_global_load_lds((gvoid*)g, (lvoid*)l, 16, 0, 0);
}

// ---------------- build x = concat(mem, hidden) ----------------
__global__ __launch_bounds__(256) void build_x(const float* __restrict__ hs,
                                               const float* __restrict__ mem,
                                               float* __restrict__ xf,
                                               u16* __restrict__ xb) {
  const long i  = (long)blockIdx.x * 256 + threadIdx.x;   // float4 index
  const int row = (int)(i >> 8);
  const int c4  = (int)(i & 255);
  const int bb  = row >> 10, t = row & 1023;
  f32x4 v;
  if (t < M_) v = ((const f32x4*)(mem + (long)t * D_))[c4];
  else        v = ((const f32x4*)(hs + (long)(bb * S_ + (t - M_)) * D_))[c4];
  ((f32x4*)xf)[i] = v;
  u16x4 ob;
  #pragma unroll
  for (int c = 0; c < 4; c++) ob[c] = f2bf(v[c]);
  ((u16x4*)xb)[i] = ob;
}

// ---------------- weight transpose fp32(KxN) -> bf16(NxK) ----------------
__global__ __launch_bounds__(256) void wtrans(const float* __restrict__ W,
                                              u16* __restrict__ WT, int K, int N) {
  __shared__ float t[32][33];
  const int n0 = blockIdx.x * 32, k0 = blockIdx.y * 32;
  const int tx = threadIdx.x, ty = threadIdx.y;
  #pragma unroll
  for (int r = 0; r < 32; r += 8)
    t[ty + r][tx] = W[(long)(k0 + ty + r) * N + n0 + tx];
  __syncthreads();
  #pragma unroll
  for (int r = 0; r < 32; r += 8)
    WT[(long)(n0 + ty + r) * K + k0 + tx] = f2bf(t[tx][ty + r]);
}

// ---------------- LayerNorm over summed split-K partials + bias + residual ----------------
// y = p0+p1+p2 + bias + resid; LN(y) -> xf (f32) + xb (bf16). p0/p1/p2 MUST be
// contiguous 16MB slabs (epilogue writes of + z*M*N).
__global__ __launch_bounds__(256) void lnred_k(const float* __restrict__ p0,
                                               const float* __restrict__ p1,
                                               const float* __restrict__ p2,
                                               const float* __restrict__ bias,
                                               const float* __restrict__ resid,
                                               const float* __restrict__ ga,
                                               const float* __restrict__ be,
                                               float* __restrict__ xf,
                                               u16* __restrict__ xb) {
  const int row = blockIdx.x, tid = threadIdx.x;
  const long ro = (long)row * D_;
  f32x4 v = ((const f32x4*)(p0 + ro))[tid];
  const f32x4 v1 = ((const f32x4*)(p1 + ro))[tid];
  const f32x4 v2 = ((const f32x4*)(p2 + ro))[tid];
  const f32x4 bi = ((const f32x4*)bias)[tid];
  const f32x4 rs4 = ((const f32x4*)(resid + ro))[tid];
  #pragma unroll
  for (int c = 0; c < 4; c++) v[c] = v[c] + v1[c] + v2[c] + bi[c] + rs4[c];
  float s  = v[0] + v[1] + v[2] + v[3];
  float ss = v[0]*v[0] + v[1]*v[1] + v[2]*v[2] + v[3]*v[3];
  #pragma unroll
  for (int m = 1; m < 64; m <<= 1) { s += __shfl_xor(s, m); ss += __shfl_xor(ss, m); }
  __shared__ float sm[8];
  if ((tid & 63) == 0) { sm[tid >> 6] = s; sm[4 + (tid >> 6)] = ss; }
  __syncthreads();
  s  = sm[0] + sm[1] + sm[2] + sm[3];
  ss = sm[4] + sm[5] + sm[6] + sm[7];
  const float mu  = s * (1.0f / D_);
  const float var = ss * (1.0f / D_) - mu * mu;
  const float rs  = rsqrtf(var + 1e-12f);
  const f32x4 gg = ((const f32x4*)ga)[tid];
  const f32x4 bb = ((const f32x4*)be)[tid];
  f32x4 o; u16x4 ob;
  #pragma unroll
  for (int c = 0; c < 4; c++) { o[c] = (v[c] - mu) * rs * gg[c] + bb[c]; ob[c] = f2bf(o[c]); }
  ((f32x4*)(xf + ro))[tid] = o;
  ((u16x4*)(xb + ro))[tid] = ob;
}

// ---------------- copy read_out ----------------
__global__ __launch_bounds__(256) void copy_ro(const float* __restrict__ xf,
                                               float* __restrict__ dst) {
  const long i  = (long)blockIdx.x * 256 + threadIdx.x;   // float4 idx
  const int row = (int)(i >> 8);
  const int c4  = (int)(i & 255);
  const int bb  = row >> 7, t = row & 127;
  f32x4 v = ((const f32x4*)(xf + (long)(bb * T_ + t) * D_))[c4];
  ((f32x4*)dst)[i] = v;
}

// ---------------- GEMM: C = A(bf16 MxK) @ BT(bf16 NxK)^T ----------------
// R6: T3-minimum 2-phase double-buffer -- STAGE(t+1) issued BEFORE compute(t),
// ONE __syncthreads per K-step (implies vmcnt(0) drain = next tile visible AND
// all waves done reading the buffer STAGE(t+2) will overwrite). Catalog recipe;
// m228d: 622 TF refcheck'd at 128^2+2ph vs ~360 for the 1-phase version.
// EPI: 0=QKV scatter  2=bias+gelu->bf16  3=bias+gelu->f32  4=split-K partial f32
// RMAP: 1 = final projector A-row remap (skip mem rows)
template <int EPI, int RMAP>
__global__ __launch_bounds__(256) void gemm_bt(const u16* __restrict__ A,
                                               const u16* __restrict__ BT,
                                               const float* __restrict__ bias0,
                                               const float* __restrict__ bias1,
                                               const float* __restrict__ bias2,
                                               float* __restrict__ of,
                                               u16* __restrict__ ob0,
                                               u16* __restrict__ ob1,
                                               u16* __restrict__ ob2,
                                               int M, int N, int K, int KC) {
  __shared__ u16 As[2 * 128 * 32];    // 2 x 8 KB
  __shared__ u16 Bs[2 * 128 * 32];    // 2 x 8 KB  (32 KB total -> 5 blocks/CU cap)
  const int tid = threadIdx.x;
  const int l   = tid & 63;
  const int w   = tid >> 6;
  const int r16 = l & 15;
  const int g   = l >> 4;
  const int bm = blockIdx.x, bn = blockIdx.y;

  const int kstart = (EPI == 4) ? blockIdx.z * KC : 0;
  const int klen   = (EPI == 4) ? min(KC, K - kstart) : K;

  // staging coords: chunk(w)/(w+4), each lane 16B
  const int srow0 = w * 16 + (l >> 2);
  const int srow1 = srow0 + 64;
  const int scol  = (l & 3) * 8;
  long ar0 = (long)bm * 128 + srow0;
  long ar1 = (long)bm * 128 + srow1;
  if (RMAP == 1) {                       // R -> b*1024 + 128 + R%896
    int R0 = (int)ar0, R1 = (int)ar1;
    ar0 = (long)(R0 / 896) * 1024 + 128 + (R0 % 896);
    ar1 = (long)(R1 / 896) * 1024 + 128 + (R1 % 896);
  }
  const u16* Ag0 = A + ar0 * K + kstart + scol;
  const u16* Ag1 = A + ar1 * K + kstart + scol;
  const u16* Bg0 = BT + ((long)bn * 128 + srow0) * K + kstart + scol;
  const u16* Bg1 = BT + ((long)bn * 128 + srow1) * K + kstart + scol;
  const int sd0 = w * 512, sd1 = (w + 4) * 512;

  const int wm = w >> 1, wn = w & 1;
  const int aro = (wm * 64 + r16) * 32 + g * 8;
  const int bro = (wn * 64 + r16) * 32 + g * 8;

  f32x4 acc[4][4];
  #pragma unroll
  for (int i = 0; i < 4; i++)
    #pragma unroll
    for (int j = 0; j < 4; j++) acc[i][j] = (f32x4){0.f, 0.f, 0.f, 0.f};

  const int nt = klen >> 5;              // K-tiles of 32 (klen always %32==0)
  // prologue: stage tile 0 into buffer 0
  gld16(Ag0, As + sd0);
  gld16(Ag1, As + sd1);
  gld16(Bg0, Bs + sd0);
  gld16(Bg1, Bs + sd1);
  __syncthreads();                       // vmcnt(0) drain + barrier (compiler)

  int cur = 0;
  for (int kt = 0; kt < nt; ++kt) {
    const int nxt = cur ^ 1;
    if (kt + 1 < nt) {                   // issue next tile BEFORE compute (overlap)
      const int ko = (kt + 1) << 5;
      gld16(Ag0 + ko, As + nxt * 4096 + sd0);
      gld16(Ag1 + ko, As + nxt * 4096 + sd1);
      gld16(Bg0 + ko, Bs + nxt * 4096 + sd0);
      gld16(Bg1 + ko, Bs + nxt * 4096 + sd1);
    }
    const u16* Asr = As + cur * 4096;
    const u16* Bsr = Bs + cur * 4096;
    bf16x8 af[4], bfr[4];
    #pragma unroll
    for (int i = 0; i < 4; i++) af[i]  = *(const bf16x8*)&Asr[aro + i * 512];
    #pragma unroll
    for (int j = 0; j < 4; j++) bfr[j] = *(const bf16x8*)&Bsr[bro + j * 512];
    #pragma unroll
    for (int i = 0; i < 4; i++)
      #pragma unroll
      for (int j = 0; j < 4; j++)
        acc[i][j] = __builtin_amdgcn_mfma_f32_16x16x32_bf16(af[i], bfr[j], acc[i][j], 0, 0, 0);
    __syncthreads();                     // next tile landed + buf[cur] free for reuse
    cur = nxt;
  }

  // epilogue: C[row=(l>>4)*4+rr][col=l&15] per 16x16 tile (m89/m91 layout)
  float* pof = (EPI == 4) ? of + (long)blockIdx.z * ((long)M * N) : of;
  #pragma unroll
  for (int i = 0; i < 4; i++) {
    const int grow0 = bm * 128 + wm * 64 + i * 16 + g * 4;
    #pragma unroll
    for (int j = 0; j < 4; j++) {
      const int gcol = bn * 128 + wn * 64 + j * 16 + r16;
      f32x4 v = acc[i][j];
      if (EPI == 0) {
        const int bb = grow0 >> 10, t0 = grow0 & 1023;
        if (gcol < 1024) {                       // Q (pre-scaled by 1/8)
          const float bi = bias0[gcol];
          const int h = gcol >> 6, d = gcol & 63;
          u16* dst = ob0 + ((long)(bb * H_ + h) * T_) * DH + d;
          #pragma unroll
          for (int rr = 0; rr < 4; rr++) dst[(long)(t0 + rr) * DH] = f2bf((v[rr] + bi) * 0.125f);
        } else if (gcol < 2048) {                // K
          const int c = gcol - 1024;
          const float bi = bias1[c];
          const int h = c >> 6, d = c & 63;
          u16* dst = ob1 + ((long)(bb * H_ + h) * T_) * DH + d;
          #pragma unroll
          for (int rr = 0; rr < 4; rr++) dst[(long)(t0 + rr) * DH] = f2bf(v[rr] + bi);
        } else {                                 // V -> transposed (bh, d, t)
          const int c = gcol - 2048;
          const float bi = bias2[c];
          const int h = c >> 6, d = c & 63;
          u16x4 pk;
          #pragma unroll
          for (int rr = 0; rr < 4; rr++) pk[rr] = f2bf(v[rr] + bi);
          *(u16x4*)(ob2 + ((long)(bb * H_ + h) * DH + d) * T_ + t0) = pk;
        }
      } else if (EPI == 2) {
        const float bi = bias0[gcol];
        #pragma unroll
        for (int rr = 0; rr < 4; rr++)
          ob0[(long)(grow0 + rr) * N + gcol] = f2bf(geluf(v[rr] + bi));
      } else if (EPI == 3) {
        const float bi = bias0[gcol];
        #pragma unroll
        for (int rr = 0; rr < 4; rr++)
          of[(long)(grow0 + rr) * N + gcol] = geluf(v[rr] + bi);
      } else {                                   // EPI==4: raw partial
        #pragma unroll
        for (int rr = 0; rr < 4; rr++)
          pof[(long)(grow0 + rr) * N + gcol] = v[rr];
      }
    }
  }
}

// ---------------- fused flash attention (swapped 32x32, zero-DS hot loop) ----------------
__global__ __launch_bounds__(256) void attn_k(const u16* __restrict__ qB,
                                              const u16* __restrict__ kB,
                                              const u16* __restrict__ vT,
                                              u16* __restrict__ ctx) {
  const int l   = threadIdx.x & 63, w = threadIdx.x >> 6;
  const int q31 = l & 31, hl = l >> 5;
  const int bh  = blockIdx.y, bb = bh >> 4, h = bh & 15;
  const int qbase = (blockIdx.x * 4 + w) * 32;
  const u16* qh = qB + (long)bh * T_ * DH;
  const u16* kh = kB + (long)bh * T_ * DH;
  const u16* vh = vT + (long)bh * DH * T_;

  // Q B-frags (n=q=lane&31, k=d=d0*16+hl*8+i), loaded once
  bf16x8 qf[4];
  #pragma unroll
  for (int d0 = 0; d0 < 4; d0++)
    qf[d0] = *(const bf16x8*)&qh[(qbase + q31) * DH + d0 * 16 + hl * 8];

  f32x16 ot0, ot1;
  #pragma unroll
  for (int i = 0; i < 16; i++) { ot0[i] = 0.f; ot1[i] = 0.f; }
  float m = -1e30f, lsum = 0.f;

  for (int kb0 = 0; kb0 < T_; kb0 += 32) {
    // V^T A-frags (m=d=lane&31 within tile, k=key=(hl)*8+i), issue early
    bf16x8 vf0a = *(const bf16x8*)&vh[q31 * T_ + kb0 + hl * 8];
    bf16x8 vf0b = *(const bf16x8*)&vh[q31 * T_ + kb0 + 16 + hl * 8];
    bf16x8 vf1a = *(const bf16x8*)&vh[(32 + q31) * T_ + kb0 + hl * 8];
    bf16x8 vf1b = *(const bf16x8*)&vh[(32 + q31) * T_ + kb0 + 16 + hl * 8];

    // S^T = K @ Q^T over DH=64 (4 x K=16)
    f32x16 st;
    #pragma unroll
    for (int i = 0; i < 16; i++) st[i] = 0.f;
    #pragma unroll
    for (int d0 = 0; d0 < 4; d0++) {
      bf16x8 kf = *(const bf16x8*)&kh[(kb0 + q31) * DH + d0 * 16 + hl * 8];
      st = __builtin_amdgcn_mfma_f32_32x32x16_bf16(kf, qf[d0], st, 0, 0, 0);
    }

    // row max: in-lane tree over 16, then cross-half swap (VALU) + max
    float x0 = fmaxf(st[0], st[1]),   x1 = fmaxf(st[2], st[3]);
    float x2 = fmaxf(st[4], st[5]),   x3 = fmaxf(st[6], st[7]);
    float x4 = fmaxf(st[8], st[9]),   x5 = fmaxf(st[10], st[11]);
    float x6 = fmaxf(st[12], st[13]), x7 = fmaxf(st[14], st[15]);
    float pm = fmaxf(fmaxf(fmaxf(x0, x1), fmaxf(x2, x3)),
                     fmaxf(fmaxf(x4, x5), fmaxf(x6, x7)));
    {
      float a = pm, b = pm;
      asm("v_permlane32_swap_b32 %0, %1" : "+v"(a), "+v"(b));
      pm = fmaxf(a, b);
    }

    // defer-max (T13, THR=8): only rescale when the running max grew enough
    if (!__all(pm <= m + 8.0f)) {
      const float nm = fmaxf(m, pm);
      const float sc = __expf(m - nm);
      m = nm;
      lsum *= sc;
      #pragma unroll
      for (int i = 0; i < 16; i++) { ot0[i] *= sc; ot1[i] *= sc; }
    }

    // P = exp(S - m), row sum (in-lane + swap)
    float p[16], sum = 0.f;
    #pragma unroll
    for (int i = 0; i < 16; i++) { p[i] = __expf(st[i] - m); sum += p[i]; }
    {
      float a = sum, b = sum;
      asm("v_permlane32_swap_b32 %0, %1" : "+v"(a), "+v"(b));
      sum = a + b;
    }
    lsum += sum;

    // pack P -> bf16 B-frags: pk[i] = cvt_pk(p[2i], p[2i+1]); swap pairs (T12)
    u32 pk[8];
    #pragma unroll
    for (int i = 0; i < 8; i++)
      asm("v_cvt_pk_bf16_f32 %0, %1, %2" : "=v"(pk[i]) : "v"(p[2 * i]), "v"(p[2 * i + 1]));
    asm("v_permlane32_swap_b32 %0, %1" : "+v"(pk[0]), "+v"(pk[2]));
    asm("v_permlane32_swap_b32 %0, %1" : "+v"(pk[1]), "+v"(pk[3]));
    asm("v_permlane32_swap_b32 %0, %1" : "+v"(pk[4]), "+v"(pk[6]));
    asm("v_permlane32_swap_b32 %0, %1" : "+v"(pk[5]), "+v"(pk[7]));
    union { u32 u[4]; bf16x8 v; } f1, f2;
    f1.u[0] = pk[0]; f1.u[1] = pk[1]; f1.u[2] = pk[2]; f1.u[3] = pk[3];
    f2.u[0] = pk[4]; f2.u[1] = pk[5]; f2.u[2] = pk[6]; f2.u[3] = pk[7];

    // O^T += V^T @ P^T  (keys 0-15 then 16-31)
    ot0 = __builtin_amdgcn_mfma_f32_32x32x16_bf16(vf0a, f1.v, ot0, 0, 0, 0);
    ot0 = __builtin_amdgcn_mfma_f32_32x32x16_bf16(vf0b, f2.v, ot0, 0, 0, 0);
    ot1 = __builtin_amdgcn_mfma_f32_32x32x16_bf16(vf1a, f1.v, ot1, 0, 0, 0);
    ot1 = __builtin_amdgcn_mfma_f32_32x32x16_bf16(vf1b, f2.v, ot1, 0, 0, 0);
  }

  const float inv = 1.0f / lsum;
  u16* dst = ctx + ((long)(bb * T_ + qbase + q31)) * D_ + h * DH;
  #pragma unroll
  for (int rg = 0; rg < 4; rg++) {
    u16x4 o0, o1;
    #pragma unroll
    for (int r = 0; r < 4; r++) {
      o0[r] = f2bf(ot0[rg * 4 + r] * inv);
      o1[r] = f2bf(ot1[rg * 4 + r] * inv);
    }
    const int d0 = rg * 8 + hl * 4;        // d=(reg&3)+8*(reg>>2)+4*hl
    *(u16x4*)(dst + d0) = o0;
    *(u16x4*)(dst + 32 + d0) = o1;
  }
}

// ---------------- host ----------------
extern "C" void kernel_launch(void* const* d_in, const int* in_sizes, int n_in,
                              void* d_out, int out_size, void* d_ws, size_t ws_size,
                              hipStream_t stream) {
  const float* hs  = (const float*)d_in[0];
  const float* mem = (const float*)d_in[1];
  const float* Wq  = (const float*)d_in[2];
  const float* bq  = (const float*)d_in[3];
  const float* Wk  = (const float*)d_in[4];
  const float* bk  = (const float*)d_in[5];
  const float* Wv  = (const float*)d_in[6];
  const float* bv  = (const float*)d_in[7];
  const float* Wo  = (const float*)d_in[8];
  const float* bo  = (const float*)d_in[9];
  const float* g1  = (const float*)d_in[10];
  const float* be1 = (const float*)d_in[11];
  const float* Wm  = (const float*)d_in[12];
  const float* bm  = (const float*)d_in[13];
  const float* Wr  = (const float*)d_in[14];
  const float* br  = (const float*)d_in[15];
  const float* g2  = (const float*)d_in[16];
  const float* be2 = (const float*)d_in[17];
  const float* Wp  = (const float*)d_in[18];
  const float* bp  = (const float*)d_in[19];
  float* out = (float*)d_out;

  // ---- workspace map (128 MB; partials CONTIGUOUS) ----
  char* ws = (char*)d_ws;
  float* xf  = (float*)(ws + 0);                 // 16 MB  [  0, 16M)
  u16*   xb  = (u16*)  (ws + 16777216);          //  8 MB  [ 16, 24M)
  float* p0  = (float*)(ws + 25165824);          // 16 MB  [ 24, 40M)  split-K partial 0
  float* p1  = (float*)(ws + 41943040);          // 16 MB  [ 40, 56M)  partial 1 (=p0+M*N)
  float* p2  = (float*)(ws + 58720256);          // 16 MB  [ 56, 72M)  partial 2
  u16*   qb  = (u16*)  (ws + 75497472);          //  8 MB  [ 72, 80M)
  u16*   kb2 = (u16*)  (ws + 83886080);          //  8 MB  [ 80, 88M)
  u16*   vtb = (u16*)  (ws + 92274688);          //  8 MB  [ 88, 96M)
  u16*   ctx = (u16*)  (ws + 100663296);         //  8 MB  [ 96,104M)
  u16*   ib  = qb;                               // 32 MB alias [72,104M) (qkv/ctx dead)
  // per-layer weight arena [104,128M): reused each layer
  u16*   WTqkv = (u16*)(ws + 109051904);         //  6 MB  [104,110M)
  u16*   WTo   = (u16*)(ws + 115343360);         //  2 MB  [110,112M)
  u16*   WTm   = (u16*)(ws + 117440512);         //  8 MB  [112,120M)
  u16*   WTr   = (u16*)(ws + 125829120);         //  8 MB  [120,128M)
  u16*   WTp   = WTqkv;                          //  8 MB  [104,112M) after layer loop

  const dim3 blk(256);
  const dim3 tb(32, 8);

  build_x<<<dim3(4096), blk, 0, stream>>>(hs, mem, xf, xb);

  for (int l = 0; l < L_; l++) {
    // transpose this layer's weights into the arena
    wtrans<<<dim3(32, 32), tb, 0, stream>>>(Wq + (long)l * D_ * D_, WTqkv, 1024, 1024);
    wtrans<<<dim3(32, 32), tb, 0, stream>>>(Wk + (long)l * D_ * D_, WTqkv + 1024 * 1024, 1024, 1024);
    wtrans<<<dim3(32, 32), tb, 0, stream>>>(Wv + (long)l * D_ * D_, WTqkv + 2048 * 1024, 1024, 1024);
    wtrans<<<dim3(32, 32), tb, 0, stream>>>(Wo + (long)l * D_ * D_, WTo, 1024, 1024);
    wtrans<<<dim3(128, 32), tb, 0, stream>>>(Wm + (long)l * D_ * I_, WTm, 1024, 4096);
    wtrans<<<dim3(32, 128), tb, 0, stream>>>(Wr + (long)l * I_ * D_, WTr, 4096, 1024);

    // fused QKV (768 blocks = 3/CU)
    gemm_bt<0, 0><<<dim3(32, 24), blk, 0, stream>>>(xb, WTqkv,
        bq + l * D_, bk + l * D_, bv + l * D_,
        nullptr, qb, kb2, vtb, NROW, 3072, 1024, 0);
    // attention
    attn_k<<<dim3(8, 64), blk, 0, stream>>>(qb, kb2, vtb, ctx);
    // O projection, split-K=3 (KC=352: chunks 352/352/320)
    gemm_bt<4, 0><<<dim3(32, 8, 3), blk, 0, stream>>>(ctx, WTo,
        nullptr, nullptr, nullptr,
        p0, nullptr, nullptr, nullptr, NROW, 1024, 1024, 352);
    lnred_k<<<dim3(4096), blk, 0, stream>>>(p0, p1, p2, bo + l * D_, xf,
        g1 + l * D_, be1 + l * D_, xf, xb);
    // FFN1 + gelu -> bf16 (1024 blocks = 4/CU)
    gemm_bt<2, 0><<<dim3(32, 32), blk, 0, stream>>>(xb, WTm,
        bm + l * I_, nullptr, nullptr,
        nullptr, ib, nullptr, nullptr, NROW, 4096, 1024, 0);
    // FFN2, split-K=3 (KC=1376: chunks 1376/1376/1344)
    gemm_bt<4, 0><<<dim3(32, 8, 3), blk, 0, stream>>>(ib, WTr,
        nullptr, nullptr, nullptr,
        p0, nullptr, nullptr, nullptr, NROW, 1024, 4096, 1376);
    lnred_k<<<dim3(4096), blk, 0, stream>>>(p0, p1, p2, br + l * D_, xf,
        g2 + l * D_, be2 + l * D_, xf, xb);
  }

  // final projector on non-mem rows (M=3584=28*128), + gelu -> f32 out
  wtrans<<<dim3(128, 32), tb, 0, stream>>>(Wp, WTp, 1024, 4096);
  gemm_bt<3, 1><<<dim3(28, 32), blk, 0, stream>>>(xb, WTp,
      bp, nullptr, nullptr,
      out, nullptr, nullptr, nullptr, 3584, 4096, 1024, 0);
  // read_out = x[:, :M]
  copy_ro<<<dim3(512), blk, 0, stream>>>(xf, out + 14680064);
}